// Round 1
// baseline (482.906 us; speedup 1.0000x reference)
//
#include <hip/hip_runtime.h>
#include <hip/hip_bf16.h>

// Problem constants
#define B 64
#define T 2048
#define D_Q 1024
#define D_V 512
#define ATTN 128
#define FILTERS 32
#define KSIZE 31

// ws layout (floats)
#define PQ_OFF 0                 // [B][ATTN] = 8192
#define CW_OFF 8192              // [KSIZE][ATTN] = 3968
#define PB_OFF (8192 + 3968)     // [ATTN] = 128
#define SC_OFF (8192 + 3968 + 128) // [B][T] = 131072

// d_out layout (floats)
#define AT_OFF 0                 // attention [B][D_V] = 32768
#define AL_OFF 32768             // alignment [B][T] = 131072
#define ST_OFF (32768 + 131072)  // attention_state [B][T] = 131072

__device__ __forceinline__ float tanh_fast(float x) {
    float e = __expf(2.f * x);
    return 1.f - 2.f / (e + 1.f);
}

// ---------------------------------------------------------------------------
// K1: blocks 0..63: pq[b][a] = sum_d query[b][d] * W_q[d][a]
//     block 64:     CW[k][a] = sum_f ck[k][f] * W_loc[f][a]
//                   pb[a]    = sum_f cbias[f] * W_loc[f][a] + att_bias[a]
// ---------------------------------------------------------------------------
__global__ void k1_precompute(const float* __restrict__ query,
                              const float* __restrict__ Wq,
                              const float* __restrict__ ck,
                              const float* __restrict__ cbias,
                              const float* __restrict__ Wl,
                              const float* __restrict__ abias,
                              float* __restrict__ ws) {
    int tid = threadIdx.x;  // 128 threads
    if (blockIdx.x < B) {
        int b = blockIdx.x;
        __shared__ float sq[D_Q];
        for (int i = tid; i < D_Q; i += 128) sq[i] = query[b * D_Q + i];
        __syncthreads();
        float acc = 0.f;
#pragma unroll 8
        for (int d = 0; d < D_Q; ++d) acc += sq[d] * Wq[d * ATTN + tid];
        ws[PQ_OFF + b * ATTN + tid] = acc;
    } else {
        __shared__ float swl[FILTERS * ATTN];
        for (int i = tid; i < FILTERS * ATTN; i += 128) swl[i] = Wl[i];
        __syncthreads();
        int a = tid;
        for (int k = 0; k < KSIZE; ++k) {
            float acc = 0.f;
#pragma unroll
            for (int f = 0; f < FILTERS; ++f) acc += ck[k * FILTERS + f] * swl[f * ATTN + a];
            ws[CW_OFF + k * ATTN + a] = acc;
        }
        float pb = abias[a];
#pragma unroll
        for (int f = 0; f < FILTERS; ++f) pb += cbias[f] * swl[f * ATTN + a];
        ws[PB_OFF + a] = pb;
    }
}

// ---------------------------------------------------------------------------
// K2: scores[b][t] = sum_a tanh(keys[b][t][a] + pq[b][a] + pb[a]
//                               + sum_k state[b][t+k-15]*CW[k][a]) * v_att[a]
// grid = B * (T/64) = 2048 blocks, 256 threads: a = tid&127, h = tid>>7
// thread (a,h) handles t_local in [32h, 32h+32), in 4 stages of 8.
// ---------------------------------------------------------------------------
__global__ void __launch_bounds__(256)
k2_scores(const float* __restrict__ keys,
          const float* __restrict__ state,
          const float* __restrict__ vatt,
          float* __restrict__ ws) {
    int bid = blockIdx.x;
    int b = bid >> 5;
    int t0 = (bid & 31) << 6;       // 64 t per block
    int tid = threadIdx.x;
    int a = tid & 127;
    int h = tid >> 7;

    __shared__ __align__(16) float sstate[96];
    __shared__ float sred[128];

    // state window: sstate[i] = state[b][t0 + i - 15] (0 outside)
    if (tid < 96) {
        int idx = t0 + tid - 15;
        sstate[tid] = (idx >= 0 && idx < T) ? state[b * T + idx] : 0.f;
    }

    float cw[KSIZE];
#pragma unroll
    for (int k = 0; k < KSIZE; ++k) cw[k] = ws[CW_OFF + k * ATTN + a];
    float pqa = ws[PQ_OFF + b * ATTN + a] + ws[PB_OFF + a];
    float vat = vatt[a];

    __syncthreads();

    const float* keyrow = keys + ((size_t)b * T + t0) * ATTN + a;
    const float4* sv = (const float4*)sstate;

    for (int s4 = 0; s4 < 4; ++s4) {
        int ts = h * 32 + s4 * 8;   // t_local base, multiple of 8
        // prefetch 8 keys
        float kv[8];
#pragma unroll
        for (int j = 0; j < 8; ++j) kv[j] = keyrow[(size_t)(ts + j) * ATTN];
        // state window into registers: w[m] = sstate[ts+m], m=0..39
        float w[40];
#pragma unroll
        for (int q = 0; q < 10; ++q) {
            float4 v = sv[(ts >> 2) + q];
            w[4 * q + 0] = v.x; w[4 * q + 1] = v.y;
            w[4 * q + 2] = v.z; w[4 * q + 3] = v.w;
        }
        float sc[8];
#pragma unroll
        for (int j = 0; j < 8; ++j) sc[j] = 0.f;
#pragma unroll
        for (int k = 0; k < KSIZE; ++k) {
#pragma unroll
            for (int j = 0; j < 8; ++j) sc[j] += w[j + k] * cw[k];
        }
#pragma unroll
        for (int j = 0; j < 8; ++j) {
            float x = kv[j] + pqa + sc[j];
            float c = tanh_fast(x) * vat;
            // reduce 64 lanes
#pragma unroll
            for (int off = 32; off >= 1; off >>= 1) c += __shfl_xor(c, off);
            if ((tid & 63) == 0) sred[(ts + j) * 2 + (a >> 6)] = c;
        }
    }
    __syncthreads();
    if (tid < 64)
        ws[SC_OFF + b * T + t0 + tid] = sred[tid * 2] + sred[tid * 2 + 1];
}

// ---------------------------------------------------------------------------
// K3: softmax over t per b; write alignment + attention_state; zero attention
// grid = 64 blocks, 256 threads
// ---------------------------------------------------------------------------
__global__ void __launch_bounds__(256)
k3_softmax(const float* __restrict__ state,
           const float* __restrict__ ws,
           float* __restrict__ out) {
    int b = blockIdx.x;
    int tid = threadIdx.x;
    __shared__ float sm[4];
    __shared__ float ssum[4];

    float s[8];
#pragma unroll
    for (int k = 0; k < 8; ++k) s[k] = ws[SC_OFF + b * T + tid + k * 256];

    float m = s[0];
#pragma unroll
    for (int k = 1; k < 8; ++k) m = fmaxf(m, s[k]);
#pragma unroll
    for (int off = 32; off >= 1; off >>= 1) m = fmaxf(m, __shfl_xor(m, off));
    if ((tid & 63) == 0) sm[tid >> 6] = m;
    __syncthreads();
    m = fmaxf(fmaxf(sm[0], sm[1]), fmaxf(sm[2], sm[3]));

    float e[8], lsum = 0.f;
#pragma unroll
    for (int k = 0; k < 8; ++k) { e[k] = __expf(s[k] - m); lsum += e[k]; }
#pragma unroll
    for (int off = 32; off >= 1; off >>= 1) lsum += __shfl_xor(lsum, off);
    if ((tid & 63) == 0) ssum[tid >> 6] = lsum;
    __syncthreads();
    float inv = 1.f / (ssum[0] + ssum[1] + ssum[2] + ssum[3]);

#pragma unroll
    for (int k = 0; k < 8; ++k) {
        int t = tid + k * 256;
        float al = e[k] * inv;
        out[AL_OFF + b * T + t] = al;
        out[ST_OFF + b * T + t] = al + state[b * T + t];
    }
    // zero attention region (poisoned 0xAA each launch; K4 atomicAdds into it)
    out[AT_OFF + b * D_V + tid] = 0.f;
    out[AT_OFF + b * D_V + tid + 256] = 0.f;
}

// ---------------------------------------------------------------------------
// K4: attention[b][d] += sum_t alignment[b][t] * values[b][t][d]
// grid = B * (T/64) = 2048 blocks, 256 threads: d4 = tid&127 (float4 col),
// h = tid>>7 splits the 64-t chunk in two halves; LDS combine then atomics.
// ---------------------------------------------------------------------------
__global__ void __launch_bounds__(256)
k4_attention(const float* __restrict__ values,
             float* __restrict__ out) {
    int bid = blockIdx.x;
    int b = bid >> 5;
    int t0 = (bid & 31) << 6;
    int tid = threadIdx.x;
    int d4 = tid & 127;
    int h = tid >> 7;

    __shared__ float sal[64];
    __shared__ float4 spart[128];

    if (tid < 64) sal[tid] = out[AL_OFF + b * T + t0 + tid];
    __syncthreads();

    const float4* V = (const float4*)values + ((size_t)b * T + t0) * (D_V / 4) + d4;
    float4 acc = make_float4(0.f, 0.f, 0.f, 0.f);
#pragma unroll 8
    for (int i = 0; i < 32; ++i) {
        int tl = h * 32 + i;
        float al = sal[tl];
        float4 v = V[(size_t)tl * (D_V / 4)];
        acc.x += al * v.x; acc.y += al * v.y;
        acc.z += al * v.z; acc.w += al * v.w;
    }
    if (h == 1) spart[d4] = acc;
    __syncthreads();
    if (h == 0) {
        float4 o = spart[d4];
        acc.x += o.x; acc.y += o.y; acc.z += o.z; acc.w += o.w;
        float* dst = out + AT_OFF + b * D_V + d4 * 4;
        atomicAdd(dst + 0, acc.x);
        atomicAdd(dst + 1, acc.y);
        atomicAdd(dst + 2, acc.z);
        atomicAdd(dst + 3, acc.w);
    }
}

extern "C" void kernel_launch(void* const* d_in, const int* in_sizes, int n_in,
                              void* d_out, int out_size, void* d_ws, size_t ws_size,
                              hipStream_t stream) {
    const float* query  = (const float*)d_in[0];
    const float* values = (const float*)d_in[1];
    const float* keys   = (const float*)d_in[2];
    const float* state  = (const float*)d_in[3];
    const float* Wq     = (const float*)d_in[4];
    const float* ck     = (const float*)d_in[5];
    const float* cbias  = (const float*)d_in[6];
    const float* Wl     = (const float*)d_in[7];
    const float* vatt   = (const float*)d_in[8];
    const float* abias  = (const float*)d_in[9];
    float* out = (float*)d_out;
    float* ws  = (float*)d_ws;

    k1_precompute<<<B + 1, 128, 0, stream>>>(query, Wq, ck, cbias, Wl, abias, ws);
    k2_scores<<<B * (T / 64), 256, 0, stream>>>(keys, state, vatt, ws);
    k3_softmax<<<B, 256, 0, stream>>>(state, ws, out);
    k4_attention<<<B * (T / 64), 256, 0, stream>>>(values, out);
}

// Round 2
// 437.450 us; speedup vs baseline: 1.1039x; 1.1039x over previous
//
#include <hip/hip_runtime.h>
#include <hip/hip_bf16.h>

// Problem constants
#define B 64
#define T 2048
#define D_Q 1024
#define D_V 512
#define ATTN 128
#define FILTERS 32
#define KSIZE 31

// ws layout (floats)
#define PQ_OFF 0                 // [B][ATTN] = 8192
#define CW_OFF 8192              // [KSIZE][ATTN] = 3968
#define PB_OFF (8192 + 3968)     // [ATTN] = 128
#define SC_OFF (8192 + 3968 + 128) // [B][T] = 131072

// d_out layout (floats)
#define AT_OFF 0                 // attention [B][D_V] = 32768
#define AL_OFF 32768             // alignment [B][T] = 131072
#define ST_OFF (32768 + 131072)  // attention_state [B][T] = 131072

__device__ __forceinline__ float tanh_fast(float x) {
    float e = __expf(2.f * x);
    return 1.f - 2.f / (e + 1.f);
}

// ---------------------------------------------------------------------------
// K1: blocks 0..63: pq[b][a] = sum_d query[b][d] * W_q[d][a]
//   256 threads: q = tid&31 (a-quad, 4 a's via float4), s = tid>>5 (d-slice,
//   128 d each). 128 independent float4 loads per thread -> high MLP,
//   fully coalesced (lanes 0..31 cover one 512B row segment).
// block 64: CW[k][a] = sum_f ck[k][f]*W_loc[f][a]; pb[a] = cbias@W_loc + abias
// ---------------------------------------------------------------------------
__global__ void __launch_bounds__(256)
k1_precompute(const float* __restrict__ query,
              const float* __restrict__ Wq,
              const float* __restrict__ ck,
              const float* __restrict__ cbias,
              const float* __restrict__ Wl,
              const float* __restrict__ abias,
              float* __restrict__ ws) {
    int tid = threadIdx.x;
    if (blockIdx.x < B) {
        int b = blockIdx.x;
        int q = tid & 31;    // a-quad index: a = 4q..4q+3
        int s = tid >> 5;    // d-slice: d in [128s, 128s+128)
        __shared__ __align__(16) float sq[D_Q];
        __shared__ float4 red[256];
        ((float4*)sq)[tid] = ((const float4*)(query + (size_t)b * D_Q))[tid];
        __syncthreads();

        const float4* Wq4 = (const float4*)Wq;  // [D_Q][32]
        float4 acc = make_float4(0.f, 0.f, 0.f, 0.f);
        int dbase = s << 7;
#pragma unroll 16
        for (int i = 0; i < 128; ++i) {
            int d = dbase + i;
            float sd = sq[d];
            float4 w = Wq4[(size_t)d * 32 + q];
            acc.x += sd * w.x; acc.y += sd * w.y;
            acc.z += sd * w.z; acc.w += sd * w.w;
        }
        red[tid] = acc;
        __syncthreads();
        if (tid < 128) {
            float4 o = red[tid + 128];
            acc = red[tid];
            acc.x += o.x; acc.y += o.y; acc.z += o.z; acc.w += o.w;
            red[tid] = acc;
        }
        __syncthreads();
        if (tid < 64) {
            float4 o = red[tid + 64];
            acc = red[tid];
            acc.x += o.x; acc.y += o.y; acc.z += o.z; acc.w += o.w;
            red[tid] = acc;
        }
        __syncthreads();
        if (tid < 32) {
            float4 o = red[tid + 32];
            acc = red[tid];
            acc.x += o.x; acc.y += o.y; acc.z += o.z; acc.w += o.w;
            ((float4*)(ws + PQ_OFF))[b * 32 + tid] = acc;
        }
    } else {
        __shared__ float swl[FILTERS * ATTN];
        for (int i = tid; i < FILTERS * ATTN; i += 256) swl[i] = Wl[i];
        __syncthreads();
        if (tid < ATTN) {
            int a = tid;
            for (int k = 0; k < KSIZE; ++k) {
                float acc = 0.f;
#pragma unroll
                for (int f = 0; f < FILTERS; ++f) acc += ck[k * FILTERS + f] * swl[f * ATTN + a];
                ws[CW_OFF + k * ATTN + a] = acc;
            }
            float pb = abias[a];
#pragma unroll
            for (int f = 0; f < FILTERS; ++f) pb += cbias[f] * swl[f * ATTN + a];
            ws[PB_OFF + a] = pb;
        }
    }
}

// ---------------------------------------------------------------------------
// K2: scores[b][t] = sum_a tanh(keys[b][t][a] + pq[b][a] + pb[a]
//                               + sum_k state[b][t+k-15]*CW[k][a]) * v_att[a]
// grid = B * (T/64) = 2048 blocks, 256 threads: a = tid&127, h = tid>>7
// thread (a,h) handles t_local in [32h, 32h+32), in 4 stages of 8.
// ---------------------------------------------------------------------------
__global__ void __launch_bounds__(256)
k2_scores(const float* __restrict__ keys,
          const float* __restrict__ state,
          const float* __restrict__ vatt,
          float* __restrict__ ws) {
    int bid = blockIdx.x;
    int b = bid >> 5;
    int t0 = (bid & 31) << 6;       // 64 t per block
    int tid = threadIdx.x;
    int a = tid & 127;
    int h = tid >> 7;

    __shared__ __align__(16) float sstate[96];
    __shared__ float sred[128];

    // state window: sstate[i] = state[b][t0 + i - 15] (0 outside)
    if (tid < 96) {
        int idx = t0 + tid - 15;
        sstate[tid] = (idx >= 0 && idx < T) ? state[b * T + idx] : 0.f;
    }

    float cw[KSIZE];
#pragma unroll
    for (int k = 0; k < KSIZE; ++k) cw[k] = ws[CW_OFF + k * ATTN + a];
    float pqa = ws[PQ_OFF + b * ATTN + a] + ws[PB_OFF + a];
    float vat = vatt[a];

    __syncthreads();

    const float* keyrow = keys + ((size_t)b * T + t0) * ATTN + a;
    const float4* sv = (const float4*)sstate;

    for (int s4 = 0; s4 < 4; ++s4) {
        int ts = h * 32 + s4 * 8;   // t_local base, multiple of 8
        // prefetch 8 keys
        float kv[8];
#pragma unroll
        for (int j = 0; j < 8; ++j) kv[j] = keyrow[(size_t)(ts + j) * ATTN];
        // state window into registers: w[m] = sstate[ts+m], m=0..39
        float w[40];
#pragma unroll
        for (int q = 0; q < 10; ++q) {
            float4 v = sv[(ts >> 2) + q];
            w[4 * q + 0] = v.x; w[4 * q + 1] = v.y;
            w[4 * q + 2] = v.z; w[4 * q + 3] = v.w;
        }
        float sc[8];
#pragma unroll
        for (int j = 0; j < 8; ++j) sc[j] = 0.f;
#pragma unroll
        for (int k = 0; k < KSIZE; ++k) {
#pragma unroll
            for (int j = 0; j < 8; ++j) sc[j] += w[j + k] * cw[k];
        }
#pragma unroll
        for (int j = 0; j < 8; ++j) {
            float x = kv[j] + pqa + sc[j];
            float c = tanh_fast(x) * vat;
            // reduce 64 lanes
#pragma unroll
            for (int off = 32; off >= 1; off >>= 1) c += __shfl_xor(c, off);
            if ((tid & 63) == 0) sred[(ts + j) * 2 + (a >> 6)] = c;
        }
    }
    __syncthreads();
    if (tid < 64)
        ws[SC_OFF + b * T + t0 + tid] = sred[tid * 2] + sred[tid * 2 + 1];
}

// ---------------------------------------------------------------------------
// K3: softmax over t per b; write alignment + attention_state; zero attention
// grid = 64 blocks, 256 threads
// ---------------------------------------------------------------------------
__global__ void __launch_bounds__(256)
k3_softmax(const float* __restrict__ state,
           const float* __restrict__ ws,
           float* __restrict__ out) {
    int b = blockIdx.x;
    int tid = threadIdx.x;
    __shared__ float sm[4];
    __shared__ float ssum[4];

    float s[8];
#pragma unroll
    for (int k = 0; k < 8; ++k) s[k] = ws[SC_OFF + b * T + tid + k * 256];

    float m = s[0];
#pragma unroll
    for (int k = 1; k < 8; ++k) m = fmaxf(m, s[k]);
#pragma unroll
    for (int off = 32; off >= 1; off >>= 1) m = fmaxf(m, __shfl_xor(m, off));
    if ((tid & 63) == 0) sm[tid >> 6] = m;
    __syncthreads();
    m = fmaxf(fmaxf(sm[0], sm[1]), fmaxf(sm[2], sm[3]));

    float e[8], lsum = 0.f;
#pragma unroll
    for (int k = 0; k < 8; ++k) { e[k] = __expf(s[k] - m); lsum += e[k]; }
#pragma unroll
    for (int off = 32; off >= 1; off >>= 1) lsum += __shfl_xor(lsum, off);
    if ((tid & 63) == 0) ssum[tid >> 6] = lsum;
    __syncthreads();
    float inv = 1.f / (ssum[0] + ssum[1] + ssum[2] + ssum[3]);

#pragma unroll
    for (int k = 0; k < 8; ++k) {
        int t = tid + k * 256;
        float al = e[k] * inv;
        out[AL_OFF + b * T + t] = al;
        out[ST_OFF + b * T + t] = al + state[b * T + t];
    }
    // zero attention region (poisoned 0xAA each launch; K4 atomicAdds into it)
    out[AT_OFF + b * D_V + tid] = 0.f;
    out[AT_OFF + b * D_V + tid + 256] = 0.f;
}

// ---------------------------------------------------------------------------
// K4: attention[b][d] += sum_t alignment[b][t] * values[b][t][d]
// grid = B * (T/64) = 2048 blocks, 256 threads: d4 = tid&127 (float4 col),
// h = tid>>7 splits the 64-t chunk in two halves; LDS combine then atomics.
// ---------------------------------------------------------------------------
__global__ void __launch_bounds__(256)
k4_attention(const float* __restrict__ values,
             float* __restrict__ out) {
    int bid = blockIdx.x;
    int b = bid >> 5;
    int t0 = (bid & 31) << 6;
    int tid = threadIdx.x;
    int d4 = tid & 127;
    int h = tid >> 7;

    __shared__ float sal[64];
    __shared__ float4 spart[128];

    if (tid < 64) sal[tid] = out[AL_OFF + b * T + t0 + tid];
    __syncthreads();

    const float4* V = (const float4*)values + ((size_t)b * T + t0) * (D_V / 4) + d4;
    float4 acc = make_float4(0.f, 0.f, 0.f, 0.f);
#pragma unroll 8
    for (int i = 0; i < 32; ++i) {
        int tl = h * 32 + i;
        float al = sal[tl];
        float4 v = V[(size_t)tl * (D_V / 4)];
        acc.x += al * v.x; acc.y += al * v.y;
        acc.z += al * v.z; acc.w += al * v.w;
    }
    if (h == 1) spart[d4] = acc;
    __syncthreads();
    if (h == 0) {
        float4 o = spart[d4];
        acc.x += o.x; acc.y += o.y; acc.z += o.z; acc.w += o.w;
        float* dst = out + AT_OFF + b * D_V + d4 * 4;
        atomicAdd(dst + 0, acc.x);
        atomicAdd(dst + 1, acc.y);
        atomicAdd(dst + 2, acc.z);
        atomicAdd(dst + 3, acc.w);
    }
}

extern "C" void kernel_launch(void* const* d_in, const int* in_sizes, int n_in,
                              void* d_out, int out_size, void* d_ws, size_t ws_size,
                              hipStream_t stream) {
    const float* query  = (const float*)d_in[0];
    const float* values = (const float*)d_in[1];
    const float* keys   = (const float*)d_in[2];
    const float* state  = (const float*)d_in[3];
    const float* Wq     = (const float*)d_in[4];
    const float* ck     = (const float*)d_in[5];
    const float* cbias  = (const float*)d_in[6];
    const float* Wl     = (const float*)d_in[7];
    const float* vatt   = (const float*)d_in[8];
    const float* abias  = (const float*)d_in[9];
    float* out = (float*)d_out;
    float* ws  = (float*)d_ws;

    k1_precompute<<<B + 1, 256, 0, stream>>>(query, Wq, ck, cbias, Wl, abias, ws);
    k2_scores<<<B * (T / 64), 256, 0, stream>>>(keys, state, vatt, ws);
    k3_softmax<<<B, 256, 0, stream>>>(state, ws, out);
    k4_attention<<<B * (T / 64), 256, 0, stream>>>(values, out);
}

// Round 3
// 433.064 us; speedup vs baseline: 1.1151x; 1.0101x over previous
//
#include <hip/hip_runtime.h>
#include <hip/hip_bf16.h>

// Problem constants
#define B 64
#define T 2048
#define D_Q 1024
#define D_V 512
#define ATTN 128
#define FILTERS 32
#define KSIZE 31

// ws layout (floats)
#define PQ_OFF 0                    // [B][ATTN] = 8192
#define CW_OFF 8192                 // [KSIZE][ATTN] = 3968
#define PB_OFF (8192 + 3968)        // [ATTN] = 128
#define SC_OFF (8192 + 3968 + 128)  // [B][T] = 131072
#define ML_OFF (SC_OFF + 131072)    // [B][32][2] = 4096 (chunk max, chunk sum)
#define PART_OFF (ML_OFF + 4096)    // [B][32][D_V] = 1048576 partial O

// d_out layout (floats)
#define AT_OFF 0                 // attention [B][D_V] = 32768
#define AL_OFF 32768             // alignment [B][T] = 131072
#define ST_OFF (32768 + 131072)  // attention_state [B][T] = 131072

__device__ __forceinline__ float tanh_fast(float x) {
    float e = __expf(2.f * x);
    return 1.f - 2.f / (e + 1.f);
}

// ---------------------------------------------------------------------------
// K1: blocks 0..63: pq[b][a] = query[b] @ W_q  (parallel GEMV, float4 loads)
//     block 64:     CW[k][a] = ck[k] @ W_loc ; pb[a] = cbias@W_loc + att_bias
// ---------------------------------------------------------------------------
__global__ void __launch_bounds__(256)
k1_precompute(const float* __restrict__ query,
              const float* __restrict__ Wq,
              const float* __restrict__ ck,
              const float* __restrict__ cbias,
              const float* __restrict__ Wl,
              const float* __restrict__ abias,
              float* __restrict__ ws) {
    int tid = threadIdx.x;
    if (blockIdx.x < B) {
        int b = blockIdx.x;
        int q = tid & 31;    // a-quad index: a = 4q..4q+3
        int s = tid >> 5;    // d-slice: d in [128s, 128s+128)
        __shared__ __align__(16) float sq[D_Q];
        __shared__ float4 red[256];
        ((float4*)sq)[tid] = ((const float4*)(query + (size_t)b * D_Q))[tid];
        __syncthreads();

        const float4* Wq4 = (const float4*)Wq;  // [D_Q][32]
        float4 acc = make_float4(0.f, 0.f, 0.f, 0.f);
        int dbase = s << 7;
#pragma unroll 16
        for (int i = 0; i < 128; ++i) {
            int d = dbase + i;
            float sd = sq[d];
            float4 w = Wq4[(size_t)d * 32 + q];
            acc.x += sd * w.x; acc.y += sd * w.y;
            acc.z += sd * w.z; acc.w += sd * w.w;
        }
        red[tid] = acc;
        __syncthreads();
        if (tid < 128) {
            float4 o = red[tid + 128];
            acc = red[tid];
            acc.x += o.x; acc.y += o.y; acc.z += o.z; acc.w += o.w;
            red[tid] = acc;
        }
        __syncthreads();
        if (tid < 64) {
            float4 o = red[tid + 64];
            acc = red[tid];
            acc.x += o.x; acc.y += o.y; acc.z += o.z; acc.w += o.w;
            red[tid] = acc;
        }
        __syncthreads();
        if (tid < 32) {
            float4 o = red[tid + 32];
            acc = red[tid];
            acc.x += o.x; acc.y += o.y; acc.z += o.z; acc.w += o.w;
            ((float4*)(ws + PQ_OFF))[b * 32 + tid] = acc;
        }
    } else {
        __shared__ float swl[FILTERS * ATTN];
        for (int i = tid; i < FILTERS * ATTN; i += 256) swl[i] = Wl[i];
        __syncthreads();
        if (tid < ATTN) {
            int a = tid;
            for (int k = 0; k < KSIZE; ++k) {
                float acc = 0.f;
#pragma unroll
                for (int f = 0; f < FILTERS; ++f) acc += ck[k * FILTERS + f] * swl[f * ATTN + a];
                ws[CW_OFF + k * ATTN + a] = acc;
            }
            float pb = abias[a];
#pragma unroll
            for (int f = 0; f < FILTERS; ++f) pb += cbias[f] * swl[f * ATTN + a];
            ws[PB_OFF + a] = pb;
        }
    }
}

// ---------------------------------------------------------------------------
// K2 fused: per 64-t chunk:
//   Phase A: scores[t] = sum_a tanh(keys[t][a] + pq[a] + pb[a] + conv[t][a])*v[a]
//   Phase B: chunk-local softmax m_c, l_c, weights exp(s-m_c) -> LDS
//   Phase C: partial O_c[d] = sum_t w[t] * values[t][d]  (no atomics)
// grid = B*32 = 2048 blocks, 256 threads
// ---------------------------------------------------------------------------
__global__ void __launch_bounds__(256)
k2_fused(const float* __restrict__ keys,
         const float* __restrict__ state,
         const float* __restrict__ values,
         const float* __restrict__ vatt,
         float* __restrict__ ws) {
    int bid = blockIdx.x;
    int b = bid >> 5;
    int c = bid & 31;
    int t0 = c << 6;                // 64 t per block
    int tid = threadIdx.x;
    int a = tid & 127;
    int h = tid >> 7;

    __shared__ __align__(16) float sstate[96];
    __shared__ float sred[128];
    __shared__ float sal[64];       // exp(s - m_c)
    __shared__ float4 spart[128];

    // state window: sstate[i] = state[b][t0 + i - 15] (0 outside)
    if (tid < 96) {
        int idx = t0 + tid - 15;
        sstate[tid] = (idx >= 0 && idx < T) ? state[b * T + idx] : 0.f;
    }

    float cw[KSIZE];
#pragma unroll
    for (int k = 0; k < KSIZE; ++k) cw[k] = ws[CW_OFF + k * ATTN + a];
    float pqa = ws[PQ_OFF + b * ATTN + a] + ws[PB_OFF + a];
    float vat = vatt[a];

    __syncthreads();

    const float* keyrow = keys + ((size_t)b * T + t0) * ATTN + a;
    const float4* sv = (const float4*)sstate;

    for (int s4 = 0; s4 < 4; ++s4) {
        int ts = h * 32 + s4 * 8;   // t_local base, multiple of 8
        float kv[8];
#pragma unroll
        for (int j = 0; j < 8; ++j) kv[j] = keyrow[(size_t)(ts + j) * ATTN];
        float w[40];
#pragma unroll
        for (int q = 0; q < 10; ++q) {
            float4 v = sv[(ts >> 2) + q];
            w[4 * q + 0] = v.x; w[4 * q + 1] = v.y;
            w[4 * q + 2] = v.z; w[4 * q + 3] = v.w;
        }
        float sc[8];
#pragma unroll
        for (int j = 0; j < 8; ++j) sc[j] = 0.f;
#pragma unroll
        for (int k = 0; k < KSIZE; ++k) {
#pragma unroll
            for (int j = 0; j < 8; ++j) sc[j] += w[j + k] * cw[k];
        }
#pragma unroll
        for (int j = 0; j < 8; ++j) {
            float x = kv[j] + pqa + sc[j];
            float cc = tanh_fast(x) * vat;
#pragma unroll
            for (int off = 32; off >= 1; off >>= 1) cc += __shfl_xor(cc, off);
            if ((tid & 63) == 0) sred[(ts + j) * 2 + (a >> 6)] = cc;
        }
    }
    __syncthreads();

    // Phase B: wave 0 finalizes scores + chunk-local softmax (lanes 0..63)
    if (tid < 64) {
        float s = sred[tid * 2] + sred[tid * 2 + 1];
        ws[SC_OFF + b * T + t0 + tid] = s;      // raw score for combine
        float m = s;
#pragma unroll
        for (int off = 32; off >= 1; off >>= 1) m = fmaxf(m, __shfl_xor(m, off));
        float e = __expf(s - m);
        sal[tid] = e;
        float l = e;
#pragma unroll
        for (int off = 32; off >= 1; off >>= 1) l += __shfl_xor(l, off);
        if (tid == 0) {
            ws[ML_OFF + (b * 32 + c) * 2 + 0] = m;
            ws[ML_OFF + (b * 32 + c) * 2 + 1] = l;
        }
    }
    __syncthreads();

    // Phase C: partial attention for this chunk
    int d4 = tid & 127;
    const float4* V = (const float4*)values + ((size_t)b * T + t0) * (D_V / 4) + d4;
    float4 acc = make_float4(0.f, 0.f, 0.f, 0.f);
#pragma unroll 8
    for (int i = 0; i < 32; ++i) {
        int tl = h * 32 + i;
        float al = sal[tl];
        float4 v = V[(size_t)tl * (D_V / 4)];
        acc.x += al * v.x; acc.y += al * v.y;
        acc.z += al * v.z; acc.w += al * v.w;
    }
    if (h == 1) spart[d4] = acc;
    __syncthreads();
    if (h == 0) {
        float4 o = spart[d4];
        acc.x += o.x; acc.y += o.y; acc.z += o.z; acc.w += o.w;
        ((float4*)(ws + PART_OFF))[(size_t)(b * 32 + c) * (D_V / 4) + d4] = acc;
    }
}

// ---------------------------------------------------------------------------
// K3 combine: per b: M,L over 32 chunks; attention = sum_c exp(m_c-M)*O_c / L;
// alignment = exp(s-M)/L; attention_state = alignment + state.
// grid = 64 blocks, 256 threads
// ---------------------------------------------------------------------------
__global__ void __launch_bounds__(256)
k_combine(const float* __restrict__ state,
          const float* __restrict__ ws,
          float* __restrict__ out) {
    int b = blockIdx.x;
    int tid = threadIdx.x;
    __shared__ float sw[32];
    __shared__ float sM, sinvL;

    if (tid < 32) {
        float m = ws[ML_OFF + (b * 32 + tid) * 2 + 0];
        float l = ws[ML_OFF + (b * 32 + tid) * 2 + 1];
        float M = m;
#pragma unroll
        for (int off = 16; off >= 1; off >>= 1) M = fmaxf(M, __shfl_xor(M, off));
        float wgt = __expf(m - M);
        sw[tid] = wgt;
        float L = l * wgt;
#pragma unroll
        for (int off = 16; off >= 1; off >>= 1) L += __shfl_xor(L, off);
        if (tid == 0) { sM = M; sinvL = 1.f / L; }
    }
    __syncthreads();

    float M = sM, invL = sinvL;

    // attention: 512 d over 256 threads (2 each)
#pragma unroll
    for (int r = 0; r < 2; ++r) {
        int d = tid + (r << 8);
        float acc = 0.f;
#pragma unroll 8
        for (int c = 0; c < 32; ++c)
            acc += sw[c] * ws[PART_OFF + (size_t)(b * 32 + c) * D_V + d];
        out[AT_OFF + b * D_V + d] = acc * invL;
    }

    // alignment + attention_state: 2048 t over 256 threads (8 each)
#pragma unroll
    for (int k = 0; k < 8; ++k) {
        int t = tid + (k << 8);
        float s = ws[SC_OFF + b * T + t];
        float al = __expf(s - M) * invL;
        out[AL_OFF + b * T + t] = al;
        out[ST_OFF + b * T + t] = al + state[b * T + t];
    }
}

extern "C" void kernel_launch(void* const* d_in, const int* in_sizes, int n_in,
                              void* d_out, int out_size, void* d_ws, size_t ws_size,
                              hipStream_t stream) {
    const float* query  = (const float*)d_in[0];
    const float* values = (const float*)d_in[1];
    const float* keys   = (const float*)d_in[2];
    const float* state  = (const float*)d_in[3];
    const float* Wq     = (const float*)d_in[4];
    const float* ck     = (const float*)d_in[5];
    const float* cbias  = (const float*)d_in[6];
    const float* Wl     = (const float*)d_in[7];
    const float* vatt   = (const float*)d_in[8];
    const float* abias  = (const float*)d_in[9];
    float* out = (float*)d_out;
    float* ws  = (float*)d_ws;

    k1_precompute<<<B + 1, 256, 0, stream>>>(query, Wq, ck, cbias, Wl, abias, ws);
    k2_fused<<<B * (T / 64), 256, 0, stream>>>(keys, state, values, vatt, ws);
    k_combine<<<B, 256, 0, stream>>>(state, ws, out);
}